// Round 9
// baseline (3759.895 us; speedup 1.0000x reference)
//
#include <hip/hip_runtime.h>

typedef _Float16 f16;
typedef _Float16 f16x8 __attribute__((ext_vector_type(8)));
typedef float f32x4 __attribute__((ext_vector_type(4)));
typedef unsigned long long u64;

#define NSTEPS 512
#define NBATCH 256
#define HID 256
#define NL 3
#define NBG 8              // batch groups of 32 rows
#define NNW 8              // N-split: 32 hidden units per WG
#define ROWS 32
#define DRING 8            // ring depth (steps)
#define PITCH 260          // f16 row pitch (520B = 130 dw ~= 2 mod 32 -> 4-way A-read aliasing)
#define THREADS 256
#define BKB 15             // K-blocks of B kept in LDS (kb 15 in VGPRs)
#define FLAGSTRIDE 16      // ints per flag (64B padding)
#define NEG_INF_I (-2000000000)

#define WPACK_OFF ((size_t)16384)               // flags occupy [0, 12288)
#define WPACK_ELEMS ((size_t)64*16*64*8)        // f16 per layer
#define WPACK_SZB (WPACK_ELEMS*2)               // 1 MiB per layer
#define RING_OFF (WPACK_OFF + 3*WPACK_SZB)
#define SLOT_F16 ((size_t)ROWS*HID)             // 8192 f16 = 16KB = 2048 u64 granules
#define SLOT_Q 2048
#define RING_SZB ((size_t)NL*NBG*DRING*SLOT_F16*2)
#define WS_NEEDED (RING_OFF + RING_SZB)

__device__ __forceinline__ float sigm(float x){ return 1.f/(1.f+__expf(-x)); }
__device__ __forceinline__ float tanh_f(float x){ return 1.f - 2.f/(1.f+__expf(2.f*x)); }

// packed weights: [layer][nt(64)][kb(16)][lane(64)][e(8)] f16
// B-frag (mfma_f32_16x16x32_f16): col n = nt*16+(lane&15), k = kb*32+(lane>>4)*8+e.
// k<256 -> w_hh[n][k]; k>=256 -> w_ih[n][k-256] (0-padded past in_dim).
__global__ __launch_bounds__(256) void pack_weights(
    const float* __restrict__ wih0, const float* __restrict__ whh0,
    const float* __restrict__ wih1, const float* __restrict__ whh1,
    const float* __restrict__ wih2, const float* __restrict__ whh2,
    unsigned char* __restrict__ ws)
{
  int gid = blockIdx.x*256 + threadIdx.x;
  if (gid >= 3*64*16*64) return;
  int lane  = gid & 63;
  int kb    = (gid>>6) & 15;
  int nt    = (gid>>10) & 63;
  int layer = gid>>16;
  const float* whh = (layer==0)?whh0:((layer==1)?whh1:whh2);
  const float* wih = (layer==0)?wih0:((layer==1)?wih1:wih2);
  int indim = (layer==0)?12:256;
  int n  = nt*16 + (lane&15);
  int k0 = kb*32 + (lane>>4)*8;
  f16x8 v;
  #pragma unroll
  for (int e=0;e<8;++e){
    int k = k0+e;
    float x;
    if (k < HID) x = whh[n*HID + k];
    else { int ki = k-HID; x = (ki<indim)? wih[n*indim+ki] : 0.f; }
    v[e] = (f16)x;
  }
  f16* dst = (f16*)(ws + WPACK_OFF) + (size_t)layer*WPACK_ELEMS
           + ((size_t)(nt*16+kb)*64 + lane)*8;
  *(f16x8*)dst = v;
}

// upper K half (kb 8..8+NKBU-1), initializes acc with bias
template<int NKBU>
__device__ __forceinline__ void gates_upper(
    const f16* __restrict__ Hin, const f16* __restrict__ BstL,
    const f16x8* __restrict__ b15, const float* __restrict__ bias,
    int wm, int wn, int lane, int c16, f32x4* acc)
{
  const int arow = wm*16 + c16;
  #pragma unroll
  for (int G=0;G<4;++G){ f32x4 z={bias[G],bias[G],bias[G],bias[G]}; acc[G]=z; }
  #pragma unroll
  for (int u=0; u<NKBU; ++u){
    const int kb = 8+u;
    f16x8 a = *(const f16x8*)&Hin[arow*PITCH + u*32 + (lane>>4)*8];
    #pragma unroll
    for (int G=0; G<4; ++G){
      f16x8 b = (kb < BKB)
        ? ((const f16x8*)BstL)[ (size_t)((G*2+wn)*BKB + kb)*64 + lane ]
        : b15[G];
      acc[G] = __builtin_amdgcn_mfma_f32_16x16x32_f16(a, b, acc[G], 0,0,0);
    }
  }
}

// lower K half (kb 0..7), accumulates into acc
__device__ __forceinline__ void gates_lower(
    const f16* __restrict__ Hown, const f16* __restrict__ BstL,
    int wm, int wn, int lane, int c16, f32x4* acc)
{
  const int arow = wm*16 + c16;
  #pragma unroll
  for (int kb=0; kb<8; ++kb){
    f16x8 a = *(const f16x8*)&Hown[arow*PITCH + kb*32 + (lane>>4)*8];
    #pragma unroll
    for (int G=0; G<4; ++G){
      f16x8 b = ((const f16x8*)BstL)[ (size_t)((G*2+wn)*BKB + kb)*64 + lane ];
      acc[G] = __builtin_amdgcn_mfma_f32_16x16x32_f16(a, b, acc[G], 0,0,0);
    }
  }
}

// wave-local guarded poll: active lanes check p >= need; others pass
__device__ __forceinline__ void wave_poll(const int* p, int need, bool active){
  int guard = 0;
  for(;;){
    int v = active ? __hip_atomic_load(p, __ATOMIC_RELAXED, __HIP_MEMORY_SCOPE_AGENT)
                   : 0;
    int nd = active ? need : NEG_INF_I;
    if (__all(v >= nd)) break;
    if (++guard > (1<<20)) break;               // bounded: fail visibly, never hang
    __builtin_amdgcn_s_sleep(1);
  }
}

// 192 WGs = 3 layers x 8 batch-groups x 8 N-groups. Weights LDS-stationary.
// Cross-WG data: 8B relaxed agent atomics (LLC-coherent), no fences in loop.
// Two-phase step: A = lower-dep half (stage Hin, kb8..15), B = own-recurrent
// half (stage Hown, kb0..7, cell, publish), head off critical path.
__global__ __launch_bounds__(THREADS) void lstm_ws(
    const float* __restrict__ input,
    const float* __restrict__ bih0, const float* __restrict__ bhh0,
    const float* __restrict__ bih1, const float* __restrict__ bhh1,
    const float* __restrict__ bih2, const float* __restrict__ bhh2,
    const float* __restrict__ wlin, const float* __restrict__ blin,
    unsigned char* __restrict__ ws, float* __restrict__ out)
{
  __shared__ __attribute__((aligned(16))) f16 Bst[8*BKB*64*8];   // 122880 B
  __shared__ __attribute__((aligned(16))) f16 Hown[ROWS*PITCH];  // 16640 B
  __shared__ __attribute__((aligned(16))) f16 Hin [ROWS*PITCH];  // 16640 B
  __shared__ __attribute__((aligned(16))) f16 Hstage[ROWS*32];   // 2048 B
  __shared__ float wlinLDS[HID];                                 // 1024 B

  const int tid  = threadIdx.x;
  const int w    = tid >> 6;          // 4 waves
  const int wm   = w >> 1, wn = w & 1;
  const int lane = tid & 63;
  const int c16  = lane & 15;
  const int r0   = (lane >> 4) * 4;
  const int bid  = blockIdx.x;
  const int bg   = bid & 7;
  const int nw   = (bid >> 3) & 7;
  const int layer= bid >> 6;
  const int rowsBase = bg * ROWS;
  const int unitBase = nw * 32;

  int* flags = (int*)ws;
  int* fOwn  = flags + (layer*NBG + bg)*8*FLAGSTRIDE;
  int* fLow  = (layer>0)? flags + ((layer-1)*NBG + bg)*8*FLAGSTRIDE : fOwn;
  int* fUp   = (layer<2)? flags + ((layer+1)*NBG + bg)*8*FLAGSTRIDE : fOwn;

  const f16* wp = (const f16*)(ws + WPACK_OFF) + (size_t)layer*WPACK_ELEMS;
  u64* ringSelfQ = (u64*)(ws + RING_OFF) + (size_t)((layer*NBG + bg)*DRING)*SLOT_Q;
  u64* ringLowQ  = (layer>0)? (u64*)(ws + RING_OFF) + (size_t)(((layer-1)*NBG + bg)*DRING)*SLOT_Q : (u64*)0;

  // ---- one-time: weights -> LDS (kb<15) and regs (kb 15) ----
  const f16x8* wpv = (const f16x8*)wp;
  f16x8* Bv = (f16x8*)Bst;
  #pragma unroll
  for (int nl=0; nl<8; ++nl){
    int G = nl>>1, s = nl&1;
    int nt = G*16 + nw*2 + s;
    for (int idx=tid; idx<BKB*64; idx+=THREADS)
      Bv[(size_t)nl*BKB*64 + idx] = wpv[(size_t)nt*1024 + idx];
  }
  f16x8 b15[4];
  #pragma unroll
  for (int G=0; G<4; ++G){
    int nt = G*16 + nw*2 + wn;
    b15[G] = wpv[(size_t)nt*1024 + 15*64 + lane];
  }
  if (tid < HID) wlinLDS[tid] = wlin[tid];

  const float* BIH = (layer==0)?bih0:((layer==1)?bih1:bih2);
  const float* BHH = (layer==0)?bhh0:((layer==1)?bhh1:bhh2);
  float bias[4], cst[4];
  const int unit = unitBase + wn*16 + c16;
  #pragma unroll
  for (int G=0;G<4;++G){
    int n = G*HID + unit;
    bias[G] = BIH[n] + BHH[n];
    cst[G] = 0.f;                                   // reused as [q]
  }
  const float bl = blin[0];

  for (int i=tid; i<ROWS*PITCH; i+=THREADS){ Hown[i]=(f16)0.f; Hin[i]=(f16)0.f; }
  __syncthreads();

  for (int t=0; t<NSTEPS; ++t){
    // ======== PHASE A: lower-dependent half ========
    if (layer > 0){
      wave_poll(fLow + (lane&7)*FLAGSTRIDE, t+1, lane<8);   // lower done step t
      asm volatile("" ::: "memory");
      const u64* src = ringLowQ + (size_t)(t&(DRING-1))*SLOT_Q;
      #pragma unroll
      for (int it=0; it<8; ++it){
        int i = tid + it*THREADS;
        int row = i>>6, g = i&63;
        u64 v = __hip_atomic_load(src+i, __ATOMIC_RELAXED, __HIP_MEMORY_SCOPE_AGENT);
        *(u64*)&Hin[row*PITCH + g*4] = v;
      }
    } else {
      for (int idx=tid; idx<ROWS*12; idx+=THREADS){
        int r = idx/12, i = idx - r*12;
        Hin[r*PITCH + i] = (f16)input[((size_t)t*NBATCH + rowsBase + r)*12 + i];
      }
    }
    __syncthreads();

    f32x4 acc[4];
    if (layer==0) gates_upper<1>(Hin, Bst, b15, bias, wm, wn, lane, c16, acc);
    else          gates_upper<8>(Hin, Bst, b15, bias, wm, wn, lane, c16, acc);

    // ======== PHASE B: own-recurrent half ========
    {
      const int role = lane>>3, idx = lane&7;
      bool actOwn = (role==0) && (t>0);
      bool actUp  = (role==1) && (layer<2);
      const int* p = actOwn ? fOwn + idx*FLAGSTRIDE
                   : actUp  ? fUp  + idx*FLAGSTRIDE : fOwn;
      int need     = actOwn ? t : (actUp ? t-DRING+1 : NEG_INF_I);
      wave_poll(p, need, actOwn || actUp);
    }
    asm volatile("" ::: "memory");
    if (t > 0){
      const u64* src = ringSelfQ + (size_t)((t-1)&(DRING-1))*SLOT_Q;
      #pragma unroll
      for (int it=0; it<8; ++it){
        int i = tid + it*THREADS;
        int row = i>>6, g = i&63;
        u64 v = __hip_atomic_load(src+i, __ATOMIC_RELAXED, __HIP_MEMORY_SCOPE_AGENT);
        *(u64*)&Hown[row*PITCH + g*4] = v;
      }
    }
    __syncthreads();

    gates_lower(Hown, Bst, wm, wn, lane, c16, acc);

    const int lu = wn*16 + c16;      // local unit 0..31
    #pragma unroll
    for (int q=0;q<4;++q){
      float gi = sigm  (acc[0][q]);
      float gf = sigm  (acc[1][q]);
      float gg = tanh_f(acc[2][q]);
      float go = sigm  (acc[3][q]);
      float cv = gf*cst[q] + gi*gg; cst[q]=cv;
      float h  = go*tanh_f(cv);
      Hstage[(wm*16 + r0 + q)*32 + lu] = (f16)h;
    }
    __syncthreads();                  // Hstage complete

    // ---- publish: Hstage -> ring slot t, then flag ----
    {
      int row = tid>>3, g = tid&7;
      u64 v = *(const u64*)&Hstage[row*32 + g*4];
      u64* dst = ringSelfQ + (size_t)(t&(DRING-1))*SLOT_Q + row*64 + (unitBase>>2) + g;
      __hip_atomic_store(dst, v, __ATOMIC_RELAXED, __HIP_MEMORY_SCOPE_AGENT);
    }
    asm volatile("s_waitcnt vmcnt(0)" ::: "memory");   // per-wave: stores at LLC
    __syncthreads();                                   // all waves done
    if (tid==0)
      __hip_atomic_store(fOwn + nw*FLAGSTRIDE, t+1,
                         __ATOMIC_RELAXED, __HIP_MEMORY_SCOPE_AGENT);

    // ---- head (layer 2): out[t-1] from Hown (h_{t-1}), off critical path ----
    if (layer==2 && t>0){
      int row = tid>>3, kc = tid&7;
      float s = 0.f;
      #pragma unroll
      for (int cc=0; cc<4; ++cc){
        f16x8 hv = *(const f16x8*)&Hown[row*PITCH + kc*32 + cc*8];
        #pragma unroll
        for (int j=0;j<8;++j) s += (float)hv[j] * wlinLDS[kc*32 + cc*8 + j];
      }
      s += __shfl_xor(s,1); s += __shfl_xor(s,2); s += __shfl_xor(s,4);
      if (kc==0) out[(size_t)(t-1)*NBATCH + rowsBase + row] = s + bl;
    }
  }

  // ---- epilogue: out[511] from h_511 (layer 2) ----
  if (layer==2){
    wave_poll(fOwn + (lane&7)*FLAGSTRIDE, NSTEPS, lane<8);
    asm volatile("" ::: "memory");
    const u64* src = ringSelfQ + (size_t)((NSTEPS-1)&(DRING-1))*SLOT_Q;
    #pragma unroll
    for (int it=0; it<8; ++it){
      int i = tid + it*THREADS;
      int row = i>>6, g = i&63;
      u64 v = __hip_atomic_load(src+i, __ATOMIC_RELAXED, __HIP_MEMORY_SCOPE_AGENT);
      *(u64*)&Hown[row*PITCH + g*4] = v;
    }
    __syncthreads();
    int row = tid>>3, kc = tid&7;
    float s = 0.f;
    #pragma unroll
    for (int cc=0; cc<4; ++cc){
      f16x8 hv = *(const f16x8*)&Hown[row*PITCH + kc*32 + cc*8];
      #pragma unroll
      for (int j=0;j<8;++j) s += (float)hv[j] * wlinLDS[kc*32 + cc*8 + j];
    }
    s += __shfl_xor(s,1); s += __shfl_xor(s,2); s += __shfl_xor(s,4);
    if (kc==0) out[(size_t)(NSTEPS-1)*NBATCH + rowsBase + row] = s + bl;
  }
}

extern "C" void kernel_launch(void* const* d_in, const int* in_sizes, int n_in,
                              void* d_out, int out_size, void* d_ws, size_t ws_size,
                              hipStream_t stream)
{
  const float* input=(const float*)d_in[0];
  const float* wih0 =(const float*)d_in[1];
  const float* whh0 =(const float*)d_in[2];
  const float* bih0 =(const float*)d_in[3];
  const float* bhh0 =(const float*)d_in[4];
  const float* wih1 =(const float*)d_in[5];
  const float* whh1 =(const float*)d_in[6];
  const float* bih1 =(const float*)d_in[7];
  const float* bhh1 =(const float*)d_in[8];
  const float* wih2 =(const float*)d_in[9];
  const float* whh2 =(const float*)d_in[10];
  const float* bih2 =(const float*)d_in[11];
  const float* bhh2 =(const float*)d_in[12];
  const float* wlin =(const float*)d_in[13];
  const float* blin =(const float*)d_in[14];
  unsigned char* ws = (unsigned char*)d_ws;
  if (ws_size < WS_NEEDED) return;   // ~6.3 MB needed

  (void)hipMemsetAsync(ws, 0, WPACK_OFF, stream);   // flags
  hipLaunchKernelGGL(pack_weights, dim3(768), dim3(256), 0, stream,
                     wih0,whh0,wih1,whh1,wih2,whh2, ws);
  hipLaunchKernelGGL(lstm_ws, dim3(NL*NBG*NNW), dim3(THREADS), 0, stream,
                     input, bih0,bhh0,bih1,bhh1,bih2,bhh2, wlin, blin,
                     ws, (float*)d_out);
}

// Round 10
// 2863.048 us; speedup vs baseline: 1.3132x; 1.3132x over previous
//
#include <hip/hip_runtime.h>

typedef _Float16 f16;
typedef _Float16 f16x4 __attribute__((ext_vector_type(4)));
typedef _Float16 f16x8 __attribute__((ext_vector_type(8)));
typedef float f32x4 __attribute__((ext_vector_type(4)));
typedef unsigned long long u64;

#define NSTEPS 512
#define NBATCH 256
#define HID 256
#define NL 3
#define NBG 8              // batch groups of 32 rows
#define NNW 8              // N-split: 32 hidden units per WG
#define ROWS 32
#define DRING 8            // ring depth (steps)
#define PITCH 260          // f16 row pitch (520B -> 4-way A-read aliasing)
#define THREADS 256
#define BKB 15             // K-blocks of B kept in LDS (kb 15 in VGPRs)
#define FLAGSTRIDE 16      // ints per flag (64B padding)
#define NEG_INF_I (-2000000000)

#define WPACK_OFF ((size_t)65536)               // flags occupy [0, 49152)
#define WPACK_ELEMS ((size_t)64*16*64*8)        // f16 per layer
#define WPACK_SZB (WPACK_ELEMS*2)               // 1 MiB per layer
#define RING_OFF (WPACK_OFF + 3*WPACK_SZB)
// ring slot: granule g = rowblk*256 + unit, granule = 4 rows x 1 unit = 8B
#define SLOT_Q 2048
#define RING_SZB ((size_t)NL*NBG*DRING*SLOT_Q*8)
#define WS_NEEDED (RING_OFF + RING_SZB)

__device__ __forceinline__ float sigm(float x){ return 1.f/(1.f+__expf(-x)); }
__device__ __forceinline__ float tanh_f(float x){ return 1.f - 2.f/(1.f+__expf(2.f*x)); }

// packed weights: [layer][nt(64)][kb(16)][lane(64)][e(8)] f16
// B-frag (mfma_f32_16x16x32_f16): col n = nt*16+(lane&15), k = kb*32+(lane>>4)*8+e.
// k<256 -> w_hh[n][k]; k>=256 -> w_ih[n][k-256] (0-padded past in_dim).
__global__ __launch_bounds__(256) void pack_weights(
    const float* __restrict__ wih0, const float* __restrict__ whh0,
    const float* __restrict__ wih1, const float* __restrict__ whh1,
    const float* __restrict__ wih2, const float* __restrict__ whh2,
    unsigned char* __restrict__ ws)
{
  int gid = blockIdx.x*256 + threadIdx.x;
  if (gid >= 3*64*16*64) return;
  int lane  = gid & 63;
  int kb    = (gid>>6) & 15;
  int nt    = (gid>>10) & 63;
  int layer = gid>>16;
  const float* whh = (layer==0)?whh0:((layer==1)?whh1:whh2);
  const float* wih = (layer==0)?wih0:((layer==1)?wih1:wih2);
  int indim = (layer==0)?12:256;
  int n  = nt*16 + (lane&15);
  int k0 = kb*32 + (lane>>4)*8;
  f16x8 v;
  #pragma unroll
  for (int e=0;e<8;++e){
    int k = k0+e;
    float x;
    if (k < HID) x = whh[n*HID + k];
    else { int ki = k-HID; x = (ki<indim)? wih[n*indim+ki] : 0.f; }
    v[e] = (f16)x;
  }
  f16* dst = (f16*)(ws + WPACK_OFF) + (size_t)layer*WPACK_ELEMS
           + ((size_t)(nt*16+kb)*64 + lane)*8;
  *(f16x8*)dst = v;
}

template<int KB>
__device__ __forceinline__ void gates_mfma(
    const f16* __restrict__ Hown, const f16* __restrict__ Hin,
    const f16* __restrict__ BstL, const f16x8* __restrict__ b15,
    const float* __restrict__ bias,
    int wm, int wn, int lane, int c16, f32x4* acc)
{
  const int arow = wm*16 + c16;
  #pragma unroll
  for (int G=0;G<4;++G){ f32x4 z={bias[G],bias[G],bias[G],bias[G]}; acc[G]=z; }
  #pragma unroll
  for (int kb=0; kb<KB; ++kb){
    const f16* ap = (kb<8) ? &Hown[arow*PITCH + kb*32 + (lane>>4)*8]
                           : &Hin [arow*PITCH + (kb-8)*32 + (lane>>4)*8];
    f16x8 a = *(const f16x8*)ap;
    #pragma unroll
    for (int G=0; G<4; ++G){
      f16x8 b = (kb < BKB)
        ? ((const f16x8*)BstL)[ (size_t)((G*2+wn)*BKB + kb)*64 + lane ]
        : b15[G];
      acc[G] = __builtin_amdgcn_mfma_f32_16x16x32_f16(a, b, acc[G], 0,0,0);
    }
  }
}

// 192 WGs = 3 layers x 8 batch-groups x 8 N-groups. Weights LDS-stationary.
// Cross-WG: 8B relaxed agent atomics only (LLC-coherent, no fences).
// Per step: 1 poll, 2 barriers; per-wave flags published right after compute.
__global__ __launch_bounds__(THREADS) void lstm_ws(
    const float* __restrict__ input,
    const float* __restrict__ bih0, const float* __restrict__ bhh0,
    const float* __restrict__ bih1, const float* __restrict__ bhh1,
    const float* __restrict__ bih2, const float* __restrict__ bhh2,
    const float* __restrict__ wlin, const float* __restrict__ blin,
    unsigned char* __restrict__ ws, float* __restrict__ out)
{
  __shared__ __attribute__((aligned(16))) f16 Bst[8*BKB*64*8];   // 122880 B
  __shared__ __attribute__((aligned(16))) f16 Hown[ROWS*PITCH];  // 16640 B
  __shared__ __attribute__((aligned(16))) f16 Hin [ROWS*PITCH];  // 16640 B
  __shared__ float wlinLDS[HID];                                 // 1024 B

  const int tid  = threadIdx.x;
  const int w    = tid >> 6;          // 4 waves
  const int wm   = w >> 1, wn = w & 1;
  const int lane = tid & 63;
  const int c16  = lane & 15;
  const int r0   = (lane >> 4) * 4;
  const int bid  = blockIdx.x;
  const int bg   = bid & 7;
  const int nw   = (bid >> 3) & 7;
  const int layer= bid >> 6;
  const int rowsBase = bg * ROWS;
  const int unitBase = nw * 32;

  // per-wave flags: group(layer,bg) -> 32 flags (wg*4+wave), 64B apart
  int* flags = (int*)ws;
  int* fOwn  = flags + (layer*NBG + bg)*32*FLAGSTRIDE;
  int* fLow  = (layer>0)? flags + ((layer-1)*NBG + bg)*32*FLAGSTRIDE : fOwn;
  int* fUp   = (layer<2)? flags + ((layer+1)*NBG + bg)*32*FLAGSTRIDE : fOwn;

  const f16* wp = (const f16*)(ws + WPACK_OFF) + (size_t)layer*WPACK_ELEMS;
  u64* ringSelfQ = (u64*)(ws + RING_OFF) + (size_t)((layer*NBG + bg)*DRING)*SLOT_Q;
  u64* ringLowQ  = (layer>0)? (u64*)(ws + RING_OFF) + (size_t)(((layer-1)*NBG + bg)*DRING)*SLOT_Q : (u64*)0;

  // ---- one-time: weights -> LDS (kb<15) and regs (kb 15) ----
  const f16x8* wpv = (const f16x8*)wp;
  f16x8* Bv = (f16x8*)Bst;
  #pragma unroll
  for (int nl=0; nl<8; ++nl){
    int G = nl>>1, s = nl&1;
    int nt = G*16 + nw*2 + s;
    for (int idx=tid; idx<BKB*64; idx+=THREADS)
      Bv[(size_t)nl*BKB*64 + idx] = wpv[(size_t)nt*1024 + idx];
  }
  f16x8 b15[4];
  #pragma unroll
  for (int G=0; G<4; ++G){
    int nt = G*16 + nw*2 + wn;
    b15[G] = wpv[(size_t)nt*1024 + 15*64 + lane];
  }
  if (tid < HID) wlinLDS[tid] = wlin[tid];

  const float* BIH = (layer==0)?bih0:((layer==1)?bih1:bih2);
  const float* BHH = (layer==0)?bhh0:((layer==1)?bhh1:bhh2);
  float bias[4], cst[4];
  const int unit = unitBase + wn*16 + c16;
  #pragma unroll
  for (int G=0;G<4;++G){
    int n = G*HID + unit;
    bias[G] = BIH[n] + BHH[n];
    cst[G] = 0.f;                                   // reused as [q]
  }
  const float bl = blin[0];
  const int rowblk = wm*4 + (r0>>2);                // this lane's 4-row block

  for (int i=tid; i<ROWS*PITCH; i+=THREADS){ Hown[i]=(f16)0.f; Hin[i]=(f16)0.f; }
  __syncthreads();

  for (int t=0; t<NSTEPS; ++t){
    // ---- single poll: own(32 flags)>=t by lanes 0-31, low>=t+1 by lanes 32-63 ----
    {
      const int which = lane >> 5, fidx = lane & 31;
      bool act = (which==0) || (layer>0);
      const int* p = (which==0)? fOwn + fidx*FLAGSTRIDE : fLow + fidx*FLAGSTRIDE;
      int need = act ? ((which==0)? t : t+1) : NEG_INF_I;
      int guard = 0;
      for(;;){
        int v = act ? __hip_atomic_load(p, __ATOMIC_RELAXED, __HIP_MEMORY_SCOPE_AGENT) : 0;
        if (__all(v >= need)) break;
        if (++guard > (1<<22)) break;               // bounded: fail visibly
      }
    }
    // ---- amortized backpressure: every 4th step, up >= t-4 ----
    if (layer<2 && (t&3)==0 && t>4){
      bool act = lane < 32;
      const int* p = fUp + (lane&31)*FLAGSTRIDE;
      int need = act ? t-4 : NEG_INF_I;
      int guard = 0;
      for(;;){
        int v = act ? __hip_atomic_load(p, __ATOMIC_RELAXED, __HIP_MEMORY_SCOPE_AGENT) : 0;
        if (__all(v >= need)) break;
        if (++guard > (1<<22)) break;
      }
    }
    asm volatile("" ::: "memory");

    // ---- stage: prefetch granules to regs, scatter to LDS ----
    u64 vown[8], vin[8];
    if (t > 0){
      const u64* src = ringSelfQ + (size_t)((t-1)&(DRING-1))*SLOT_Q;
      #pragma unroll
      for (int it=0; it<8; ++it)
        vown[it] = __hip_atomic_load(src + tid + it*THREADS,
                                     __ATOMIC_RELAXED, __HIP_MEMORY_SCOPE_AGENT);
    }
    if (layer > 0){
      const u64* src = ringLowQ + (size_t)(t&(DRING-1))*SLOT_Q;
      #pragma unroll
      for (int it=0; it<8; ++it)
        vin[it] = __hip_atomic_load(src + tid + it*THREADS,
                                    __ATOMIC_RELAXED, __HIP_MEMORY_SCOPE_AGENT);
    }
    if (t > 0){
      #pragma unroll
      for (int it=0; it<8; ++it){
        int i = tid + it*THREADS, rb = i>>8, un = i&255;
        union { u64 q; f16x4 h; } u; u.q = vown[it];
        f16* base = &Hown[(rb*4)*PITCH + un];
        base[0]=u.h[0]; base[PITCH]=u.h[1]; base[2*PITCH]=u.h[2]; base[3*PITCH]=u.h[3];
      }
    }
    if (layer > 0){
      #pragma unroll
      for (int it=0; it<8; ++it){
        int i = tid + it*THREADS, rb = i>>8, un = i&255;
        union { u64 q; f16x4 h; } u; u.q = vin[it];
        f16* base = &Hin[(rb*4)*PITCH + un];
        base[0]=u.h[0]; base[PITCH]=u.h[1]; base[2*PITCH]=u.h[2]; base[3*PITCH]=u.h[3];
      }
    } else {
      for (int idx=tid; idx<ROWS*12; idx+=THREADS){
        int r = idx/12, i = idx - r*12;
        Hin[r*PITCH + i] = (f16)input[((size_t)t*NBATCH + rowsBase + r)*12 + i];
      }
    }
    __syncthreads();                                  // #1: stage -> GEMM

    // ---- gates GEMM + cell ----
    f32x4 acc[4];
    if (layer==0) gates_mfma<9> (Hown, Hin, Bst, b15, bias, wm, wn, lane, c16, acc);
    else          gates_mfma<16>(Hown, Hin, Bst, b15, bias, wm, wn, lane, c16, acc);

    union { u64 q; f16x4 h; } hout;
    #pragma unroll
    for (int q=0;q<4;++q){
      float gi = sigm  (acc[0][q]);
      float gf = sigm  (acc[1][q]);
      float gg = tanh_f(acc[2][q]);
      float go = sigm  (acc[3][q]);
      float cv = gf*cst[q] + gi*gg; cst[q]=cv;
      hout.h[q] = (f16)(go*tanh_f(cv));
    }
    // ---- publish: 1 granule store, wave-local drain, per-wave flag ----
    __hip_atomic_store(ringSelfQ + (size_t)(t&(DRING-1))*SLOT_Q + rowblk*256 + unit,
                       hout.q, __ATOMIC_RELAXED, __HIP_MEMORY_SCOPE_AGENT);
    asm volatile("s_waitcnt vmcnt(0)" ::: "memory");
    if (lane==0)
      __hip_atomic_store(fOwn + (nw*4 + w)*FLAGSTRIDE, t+1,
                         __ATOMIC_RELAXED, __HIP_MEMORY_SCOPE_AGENT);

    // ---- head (layer 2): out[t-1] from Hown (h_{t-1}), after flag ----
    if (layer==2 && t>0){
      int row = tid>>3, kc = tid&7;
      float s = 0.f;
      #pragma unroll
      for (int cc=0; cc<4; ++cc){
        f16x8 hv = *(const f16x8*)&Hown[row*PITCH + kc*32 + cc*8];
        #pragma unroll
        for (int j=0;j<8;++j) s += (float)hv[j] * wlinLDS[kc*32 + cc*8 + j];
      }
      s += __shfl_xor(s,1); s += __shfl_xor(s,2); s += __shfl_xor(s,4);
      if (kc==0) out[(size_t)(t-1)*NBATCH + rowsBase + row] = s + bl;
    }
    __syncthreads();                                  // #2: reads done -> next stage
  }

  // ---- epilogue: out[511] from h_511 (layer 2) ----
  if (layer==2){
    {
      bool act = lane < 32;
      const int* p = fOwn + (lane&31)*FLAGSTRIDE;
      int need = act ? NSTEPS : NEG_INF_I;
      int guard = 0;
      for(;;){
        int v = act ? __hip_atomic_load(p, __ATOMIC_RELAXED, __HIP_MEMORY_SCOPE_AGENT) : 0;
        if (__all(v >= need)) break;
        if (++guard > (1<<22)) break;
      }
    }
    asm volatile("" ::: "memory");
    const u64* src = ringSelfQ + (size_t)((NSTEPS-1)&(DRING-1))*SLOT_Q;
    #pragma unroll
    for (int it=0; it<8; ++it){
      int i = tid + it*THREADS, rb = i>>8, un = i&255;
      union { u64 q; f16x4 h; } u;
      u.q = __hip_atomic_load(src + i, __ATOMIC_RELAXED, __HIP_MEMORY_SCOPE_AGENT);
      f16* base = &Hown[(rb*4)*PITCH + un];
      base[0]=u.h[0]; base[PITCH]=u.h[1]; base[2*PITCH]=u.h[2]; base[3*PITCH]=u.h[3];
    }
    __syncthreads();
    int row = tid>>3, kc = tid&7;
    float s = 0.f;
    #pragma unroll
    for (int cc=0; cc<4; ++cc){
      f16x8 hv = *(const f16x8*)&Hown[row*PITCH + kc*32 + cc*8];
      #pragma unroll
      for (int j=0;j<8;++j) s += (float)hv[j] * wlinLDS[kc*32 + cc*8 + j];
    }
    s += __shfl_xor(s,1); s += __shfl_xor(s,2); s += __shfl_xor(s,4);
    if (kc==0) out[(size_t)(NSTEPS-1)*NBATCH + rowsBase + row] = s + bl;
  }
}

extern "C" void kernel_launch(void* const* d_in, const int* in_sizes, int n_in,
                              void* d_out, int out_size, void* d_ws, size_t ws_size,
                              hipStream_t stream)
{
  const float* input=(const float*)d_in[0];
  const float* wih0 =(const float*)d_in[1];
  const float* whh0 =(const float*)d_in[2];
  const float* bih0 =(const float*)d_in[3];
  const float* bhh0 =(const float*)d_in[4];
  const float* wih1 =(const float*)d_in[5];
  const float* whh1 =(const float*)d_in[6];
  const float* bih1 =(const float*)d_in[7];
  const float* bhh1 =(const float*)d_in[8];
  const float* wih2 =(const float*)d_in[9];
  const float* whh2 =(const float*)d_in[10];
  const float* bih2 =(const float*)d_in[11];
  const float* bhh2 =(const float*)d_in[12];
  const float* wlin =(const float*)d_in[13];
  const float* blin =(const float*)d_in[14];
  unsigned char* ws = (unsigned char*)d_ws;
  if (ws_size < WS_NEEDED) return;   // ~9.4 MB needed

  (void)hipMemsetAsync(ws, 0, WPACK_OFF, stream);   // flags
  hipLaunchKernelGGL(pack_weights, dim3(768), dim3(256), 0, stream,
                     wih0,whh0,wih1,whh1,wih2,whh2, ws);
  hipLaunchKernelGGL(lstm_ws, dim3(NL*NBG*NNW), dim3(THREADS), 0, stream,
                     input, bih0,bhh0,bih1,bhh1,bih2,bhh2, wlin, blin,
                     ws, (float*)d_out);
}

// Round 12
// 2662.057 us; speedup vs baseline: 1.4124x; 1.0755x over previous
//
#include <hip/hip_runtime.h>

typedef _Float16 f16;
typedef _Float16 f16x4 __attribute__((ext_vector_type(4)));
typedef _Float16 f16x8 __attribute__((ext_vector_type(8)));
typedef float f32x4 __attribute__((ext_vector_type(4)));
typedef int i32x4 __attribute__((ext_vector_type(4)));
typedef unsigned long long u64;

#define NSTEPS 512
#define NBATCH 256
#define HID 256
#define NL 3
#define NBG 8              // batch groups of 32 rows
#define NNW 8              // N-split: 32 hidden units per WG
#define ROWS 32
#define DRING 8            // ring depth (steps)
#define PITCH 260          // f16 row pitch (520B -> 4-way A-read aliasing)
#define THREADS 256
#define BKB 15             // K-blocks of B kept in LDS (kb 15 in VGPRs)
#define FLAGSTRIDE 16      // ints per progress word (64B padding)
#define NEG_INF_I (-2000000000)

#define WPACK_OFF ((size_t)65536)               // progress flags in [0, 16KB)
#define WPACK_ELEMS ((size_t)64*16*64*8)        // f16 per layer
#define WPACK_SZB (WPACK_ELEMS*2)               // 1 MiB per layer
#define RING_OFF (WPACK_OFF + 3*WPACK_SZB)
// granule = {f16x4 payload(4 rows x 1 unit), tag, pad} = 16B; 2048/slot
#define SLOT_Q 2048
#define RING_SZB ((size_t)NL*NBG*DRING*SLOT_Q*16)
#define WS_NEEDED (RING_OFF + RING_SZB)

union Gran { i32x4 v; struct { f16x4 h; int tag; int pad; } s; };

__device__ __forceinline__ float sigm(float x){ return 1.f/(1.f+__expf(-x)); }
__device__ __forceinline__ float tanh_f(float x){ return 1.f - 2.f/(1.f+__expf(2.f*x)); }

// packed weights: [layer][nt(64)][kb(16)][lane(64)][e(8)] f16
__global__ __launch_bounds__(256) void pack_weights(
    const float* __restrict__ wih0, const float* __restrict__ whh0,
    const float* __restrict__ wih1, const float* __restrict__ whh1,
    const float* __restrict__ wih2, const float* __restrict__ whh2,
    unsigned char* __restrict__ ws)
{
  int gid = blockIdx.x*256 + threadIdx.x;
  if (gid >= 3*64*16*64) return;
  int lane  = gid & 63;
  int kb    = (gid>>6) & 15;
  int nt    = (gid>>10) & 63;
  int layer = gid>>16;
  const float* whh = (layer==0)?whh0:((layer==1)?whh1:whh2);
  const float* wih = (layer==0)?wih0:((layer==1)?wih1:wih2);
  int indim = (layer==0)?12:256;
  int n  = nt*16 + (lane&15);
  int k0 = kb*32 + (lane>>4)*8;
  f16x8 v;
  #pragma unroll
  for (int e=0;e<8;++e){
    int k = k0+e;
    float x;
    if (k < HID) x = whh[n*HID + k];
    else { int ki = k-HID; x = (ki<indim)? wih[n*indim+ki] : 0.f; }
    v[e] = (f16)x;
  }
  f16* dst = (f16*)(ws + WPACK_OFF) + (size_t)layer*WPACK_ELEMS
           + ((size_t)(nt*16+kb)*64 + lane)*8;
  *(f16x8*)dst = v;
}

template<int KB>
__device__ __forceinline__ void gates_mfma(
    const f16* __restrict__ Hown, const f16* __restrict__ Hin,
    const f16* __restrict__ BstL, const f16x8* __restrict__ b15,
    const float* __restrict__ bias,
    int wm, int wn, int lane, int c16, f32x4* acc)
{
  const int arow = wm*16 + c16;
  #pragma unroll
  for (int G=0;G<4;++G){ f32x4 z={bias[G],bias[G],bias[G],bias[G]}; acc[G]=z; }
  #pragma unroll
  for (int kb=0; kb<KB; ++kb){
    const f16* ap = (kb<8) ? &Hown[arow*PITCH + kb*32 + (lane>>4)*8]
                           : &Hin [arow*PITCH + (kb-8)*32 + (lane>>4)*8];
    f16x8 a = *(const f16x8*)ap;
    #pragma unroll
    for (int G=0; G<4; ++G){
      f16x8 b = (kb < BKB)
        ? ((const f16x8*)BstL)[ (size_t)((G*2+wn)*BKB + kb)*64 + lane ]
        : b15[G];
      acc[G] = __builtin_amdgcn_mfma_f32_16x16x32_f16(a, b, acc[G], 0,0,0);
    }
  }
}

// 192 WGs = 3 layers x 8 batch-groups x 8 N-groups. Weights LDS-stationary.
// Cross-WG h moves as 16B self-validating granules (payload+tag in one LLC
// transaction, sc0 sc1): consumers poll the DATA, not a flag. 1 RTT/step.
__global__ __launch_bounds__(THREADS) void lstm_ws(
    const float* __restrict__ input,
    const float* __restrict__ bih0, const float* __restrict__ bhh0,
    const float* __restrict__ bih1, const float* __restrict__ bhh1,
    const float* __restrict__ bih2, const float* __restrict__ bhh2,
    const float* __restrict__ wlin, const float* __restrict__ blin,
    unsigned char* __restrict__ ws, float* __restrict__ out)
{
  __shared__ __attribute__((aligned(16))) f16 Bst[8*BKB*64*8];   // 122880 B
  __shared__ __attribute__((aligned(16))) f16 Hown[ROWS*PITCH];  // 16640 B
  __shared__ __attribute__((aligned(16))) f16 Hin [ROWS*PITCH];  // 16640 B
  __shared__ float wlinLDS[HID];

  const int tid  = threadIdx.x;
  const int w    = tid >> 6;          // 4 waves
  const int wm   = w >> 1, wn = w & 1;
  const int lane = tid & 63;
  const int c16  = lane & 15;
  const int r0   = (lane >> 4) * 4;
  const int bid  = blockIdx.x;
  const int bg   = bid & 7;
  const int nw   = (bid >> 3) & 7;
  const int layer= bid >> 6;
  const int rowsBase = bg * ROWS;
  const int unitBase = nw * 32;

  // progress words (backpressure only): [layer*8+bg] group of 8 (per nw)
  int* flags = (int*)ws;
  int* progSelf = flags + (layer*NBG + bg)*8*FLAGSTRIDE;
  int* progUp   = (layer<2)? flags + ((layer+1)*NBG + bg)*8*FLAGSTRIDE : progSelf;

  const f16* wp = (const f16*)(ws + WPACK_OFF) + (size_t)layer*WPACK_ELEMS;
  i32x4* ringSelf = (i32x4*)(ws + RING_OFF) + (size_t)((layer*NBG + bg)*DRING)*SLOT_Q;
  i32x4* ringLow  = (layer>0)? (i32x4*)(ws + RING_OFF) + (size_t)(((layer-1)*NBG + bg)*DRING)*SLOT_Q : (i32x4*)0;

  // ---- one-time: weights -> LDS (kb<15) and regs (kb 15) ----
  const f16x8* wpv = (const f16x8*)wp;
  f16x8* Bv = (f16x8*)Bst;
  #pragma unroll
  for (int nl=0; nl<8; ++nl){
    int G = nl>>1, s = nl&1;
    int nt = G*16 + nw*2 + s;
    for (int idx=tid; idx<BKB*64; idx+=THREADS)
      Bv[(size_t)nl*BKB*64 + idx] = wpv[(size_t)nt*1024 + idx];
  }
  f16x8 b15[4];
  #pragma unroll
  for (int G=0; G<4; ++G){
    int nt = G*16 + nw*2 + wn;
    b15[G] = wpv[(size_t)nt*1024 + 15*64 + lane];
  }
  if (tid < HID) wlinLDS[tid] = wlin[tid];

  const float* BIH = (layer==0)?bih0:((layer==1)?bih1:bih2);
  const float* BHH = (layer==0)?bhh0:((layer==1)?bhh1:bhh2);
  float bias[4], cst[4];
  const int unit = unitBase + wn*16 + c16;
  #pragma unroll
  for (int G=0;G<4;++G){
    int n = G*HID + unit;
    bias[G] = BIH[n] + BHH[n];
    cst[G] = 0.f;                                   // reused as [q]
  }
  const float bl = blin[0];
  const int rowblk = wm*4 + (lane>>4);              // this lane's 4-row block

  for (int i=tid; i<ROWS*PITCH; i+=THREADS){ Hown[i]=(f16)0.f; Hin[i]=(f16)0.f; }
  __syncthreads();

  for (int t=0; t<NSTEPS; ++t){
    // ---- amortized backpressure: every 4th step, upper progress >= t-4 ----
    if (layer<2 && (t&3)==0 && t>4){
      bool act = lane < 8;
      const int* p = progUp + (lane&7)*FLAGSTRIDE;
      int need = act ? t-4 : NEG_INF_I;
      int guard = 0;
      for(;;){
        int v = act ? __hip_atomic_load(p, __ATOMIC_RELAXED, __HIP_MEMORY_SCOPE_AGENT) : 0;
        if (__all(v >= need)) break;
        if (++guard > (1<<18)) break;               // bounded: fail visibly
        __builtin_amdgcn_s_sleep(1);
      }
    }

    // ---- layer-0 input staging (no ring) ----
    if (layer == 0){
      for (int idx=tid; idx<ROWS*12; idx+=THREADS){
        int r = idx/12, i = idx - r*12;
        Hin[r*PITCH + i] = (f16)input[((size_t)t*NBATCH + rowsBase + r)*12 + i];
      }
    }

    // ---- tag-in-band staging: poll data granules until tags current ----
    {
      Gran go[8], gl[8];
      const i32x4* srcO = ringSelf + (size_t)((t-1)&(DRING-1))*SLOT_Q + tid;
      const i32x4* srcL = (layer>0)? ringLow + (size_t)(t&(DRING-1))*SLOT_Q + tid : (i32x4*)0;
      const bool doOwn = (t>0), doLow = (layer>0);
      int guard = 0;
      for(;;){
        if (doOwn){
          #pragma unroll
          for (int it=0; it<8; ++it)
            asm volatile("global_load_dwordx4 %0, %1, off sc0 sc1"
                         : "=v"(go[it].v) : "v"(srcO + it*THREADS) : "memory");
        }
        if (doLow){
          #pragma unroll
          for (int it=0; it<8; ++it)
            asm volatile("global_load_dwordx4 %0, %1, off sc0 sc1"
                         : "=v"(gl[it].v) : "v"(srcL + it*THREADS) : "memory");
        }
        asm volatile("s_waitcnt vmcnt(0)" ::: "memory");
        __builtin_amdgcn_sched_barrier(0);
        bool ok = true;
        if (doOwn){
          #pragma unroll
          for (int it=0; it<8; ++it) ok = ok && (go[it].s.tag >= t-1);
        }
        if (doLow){
          #pragma unroll
          for (int it=0; it<8; ++it) ok = ok && (gl[it].s.tag >= t);
        }
        if (ok || ++guard > (1<<18)) break;          // guard: fail visibly
      }
      if (doOwn){
        #pragma unroll
        for (int it=0; it<8; ++it){
          int i = tid + it*THREADS, rb = i>>8, un = i&255;
          f16* base = &Hown[(rb*4)*PITCH + un];
          base[0]=go[it].s.h[0]; base[PITCH]=go[it].s.h[1];
          base[2*PITCH]=go[it].s.h[2]; base[3*PITCH]=go[it].s.h[3];
        }
      }
      if (doLow){
        #pragma unroll
        for (int it=0; it<8; ++it){
          int i = tid + it*THREADS, rb = i>>8, un = i&255;
          f16* base = &Hin[(rb*4)*PITCH + un];
          base[0]=gl[it].s.h[0]; base[PITCH]=gl[it].s.h[1];
          base[2*PITCH]=gl[it].s.h[2]; base[3*PITCH]=gl[it].s.h[3];
        }
      }
    }
    __syncthreads();                                  // #1: stage -> GEMM

    // ---- progress publish (consumption-based, off critical path) ----
    if (layer>0 && (t&3)==3 && tid==0)
      __hip_atomic_store(progSelf + nw*FLAGSTRIDE, t+1,
                         __ATOMIC_RELAXED, __HIP_MEMORY_SCOPE_AGENT);

    // ---- gates GEMM + cell ----
    f32x4 acc[4];
    if (layer==0) gates_mfma<9> (Hown, Hin, Bst, b15, bias, wm, wn, lane, c16, acc);
    else          gates_mfma<16>(Hown, Hin, Bst, b15, bias, wm, wn, lane, c16, acc);

    Gran gg;
    #pragma unroll
    for (int q=0;q<4;++q){
      float gi = sigm  (acc[0][q]);
      float gf = sigm  (acc[1][q]);
      float gg_ = tanh_f(acc[2][q]);
      float go_ = sigm  (acc[3][q]);
      float cv = gf*cst[q] + gi*gg_; cst[q]=cv;
      gg.s.h[q] = (f16)(go_*tanh_f(cv));
    }
    gg.s.tag = t; gg.s.pad = 0;
    // ---- publish: ONE self-validating 16B store, fire-and-forget ----
    {
      i32x4* dst = ringSelf + (size_t)(t&(DRING-1))*SLOT_Q + rowblk*256 + unit;
      asm volatile("global_store_dwordx4 %0, %1, off sc0 sc1"
                   :: "v"(dst), "v"(gg.v) : "memory");
    }

    // ---- head (layer 2): out[t-1] from Hown (h_{t-1}) ----
    if (layer==2 && t>0){
      int row = tid>>3, kc = tid&7;
      float s = 0.f;
      #pragma unroll
      for (int cc=0; cc<4; ++cc){
        f16x8 hv = *(const f16x8*)&Hown[row*PITCH + kc*32 + cc*8];
        #pragma unroll
        for (int j=0;j<8;++j) s += (float)hv[j] * wlinLDS[kc*32 + cc*8 + j];
      }
      s += __shfl_xor(s,1); s += __shfl_xor(s,2); s += __shfl_xor(s,4);
      if (kc==0) out[(size_t)(t-1)*NBATCH + rowsBase + row] = s + bl;
    }
    __syncthreads();                                  // #2: reads done -> next stage
  }

  // ---- epilogue: out[511] from h_511 (layer 2) ----
  if (layer==2){
    Gran go[8];
    const i32x4* srcO = ringSelf + (size_t)((NSTEPS-1)&(DRING-1))*SLOT_Q + tid;
    int guard = 0;
    for(;;){
      #pragma unroll
      for (int it=0; it<8; ++it)
        asm volatile("global_load_dwordx4 %0, %1, off sc0 sc1"
                     : "=v"(go[it].v) : "v"(srcO + it*THREADS) : "memory");
      asm volatile("s_waitcnt vmcnt(0)" ::: "memory");
      __builtin_amdgcn_sched_barrier(0);
      bool ok = true;
      #pragma unroll
      for (int it=0; it<8; ++it) ok = ok && (go[it].s.tag >= NSTEPS-1);
      if (ok || ++guard > (1<<18)) break;
    }
    #pragma unroll
    for (int it=0; it<8; ++it){
      int i = tid + it*THREADS, rb = i>>8, un = i&255;
      f16* base = &Hown[(rb*4)*PITCH + un];
      base[0]=go[it].s.h[0]; base[PITCH]=go[it].s.h[1];
      base[2*PITCH]=go[it].s.h[2]; base[3*PITCH]=go[it].s.h[3];
    }
    __syncthreads();
    int row = tid>>3, kc = tid&7;
    float s = 0.f;
    #pragma unroll
    for (int cc=0; cc<4; ++cc){
      f16x8 hv = *(const f16x8*)&Hown[row*PITCH + kc*32 + cc*8];
      #pragma unroll
      for (int j=0;j<8;++j) s += (float)hv[j] * wlinLDS[kc*32 + cc*8 + j];
    }
    s += __shfl_xor(s,1); s += __shfl_xor(s,2); s += __shfl_xor(s,4);
    if (kc==0) out[(size_t)(NSTEPS-1)*NBATCH + rowsBase + row] = s + bl;
  }
}

extern "C" void kernel_launch(void* const* d_in, const int* in_sizes, int n_in,
                              void* d_out, int out_size, void* d_ws, size_t ws_size,
                              hipStream_t stream)
{
  const float* input=(const float*)d_in[0];
  const float* wih0 =(const float*)d_in[1];
  const float* whh0 =(const float*)d_in[2];
  const float* bih0 =(const float*)d_in[3];
  const float* bhh0 =(const float*)d_in[4];
  const float* wih1 =(const float*)d_in[5];
  const float* whh1 =(const float*)d_in[6];
  const float* bih1 =(const float*)d_in[7];
  const float* bhh1 =(const float*)d_in[8];
  const float* wih2 =(const float*)d_in[9];
  const float* whh2 =(const float*)d_in[10];
  const float* bih2 =(const float*)d_in[11];
  const float* bhh2 =(const float*)d_in[12];
  const float* wlin =(const float*)d_in[13];
  const float* blin =(const float*)d_in[14];
  unsigned char* ws = (unsigned char*)d_ws;
  if (ws_size < WS_NEEDED) return;   // ~9.5 MB needed

  (void)hipMemsetAsync(ws, 0, WPACK_OFF, stream);                        // progress flags
  (void)hipMemsetAsync(ws + RING_OFF, 0xFF, RING_SZB, stream);           // ring tags = -1
  hipLaunchKernelGGL(pack_weights, dim3(768), dim3(256), 0, stream,
                     wih0,whh0,wih1,whh1,wih2,whh2, ws);
  hipLaunchKernelGGL(lstm_ws, dim3(NL*NBG*NNW), dim3(THREADS), 0, stream,
                     input, bih0,bhh0,bih1,bhh1,bih2,bhh2, wlin, blin,
                     ws, (float*)d_out);
}

// Round 14
// 2301.709 us; speedup vs baseline: 1.6335x; 1.1566x over previous
//
#include <hip/hip_runtime.h>

typedef _Float16 f16;
typedef _Float16 f16x4 __attribute__((ext_vector_type(4)));
typedef _Float16 f16x8 __attribute__((ext_vector_type(8)));
typedef float f32x4 __attribute__((ext_vector_type(4)));
typedef int i32x4 __attribute__((ext_vector_type(4)));

#define NSTEPS 512
#define NBATCH 256
#define HID 256
#define NL 3
#define NBG 8              // batch groups of 32 rows
#define NNW 8              // N-split: 32 hidden units per WG
#define ROWS 32
#define DRING 8            // ring depth (steps)
#define PITCH 260          // f16 row pitch (520B -> 4-way A-read aliasing)
#define THREADS 256
#define FLAGSTRIDE 16      // ints per progress word (64B padding)
#define NEG_INF_I (-2000000000)

#define WPACK_OFF ((size_t)65536)               // progress flags in [0, 16KB)
#define WPACK_ELEMS ((size_t)64*16*64*8)        // f16 per layer
#define WPACK_SZB (WPACK_ELEMS*2)               // 1 MiB per layer
#define RING_OFF (WPACK_OFF + 3*WPACK_SZB)
// granule = {f16x4 payload(4 rows x 1 unit), tag, pad} = 16B; 2048/slot
#define SLOT_Q 2048
#define RING_SZB ((size_t)NL*NBG*DRING*SLOT_Q*16)
#define WS_NEEDED (RING_OFF + RING_SZB)

union Gran { i32x4 v; struct { f16x4 h; int tag; int pad; } s; };

__device__ __forceinline__ float sigm(float x){ return 1.f/(1.f+__expf(-x)); }
__device__ __forceinline__ float tanh_f(float x){ return 1.f - 2.f/(1.f+__expf(2.f*x)); }

// packed weights: [layer][nt(64)][kb(16)][lane(64)][e(8)] f16
// B-frag (mfma_f32_16x16x32_f16): col n = nt*16+(lane&15), k = kb*32+(lane>>4)*8+e.
__global__ __launch_bounds__(256) void pack_weights(
    const float* __restrict__ wih0, const float* __restrict__ whh0,
    const float* __restrict__ wih1, const float* __restrict__ whh1,
    const float* __restrict__ wih2, const float* __restrict__ whh2,
    unsigned char* __restrict__ ws)
{
  int gid = blockIdx.x*256 + threadIdx.x;
  if (gid >= 3*64*16*64) return;
  int lane  = gid & 63;
  int kb    = (gid>>6) & 15;
  int nt    = (gid>>10) & 63;
  int layer = gid>>16;
  const float* whh = (layer==0)?whh0:((layer==1)?whh1:whh2);
  const float* wih = (layer==0)?wih0:((layer==1)?wih1:wih2);
  int indim = (layer==0)?12:256;
  int n  = nt*16 + (lane&15);
  int k0 = kb*32 + (lane>>4)*8;
  f16x8 v;
  #pragma unroll
  for (int e=0;e<8;++e){
    int k = k0+e;
    float x;
    if (k < HID) x = whh[n*HID + k];
    else { int ki = k-HID; x = (ki<indim)? wih[n*indim+ki] : 0.f; }
    v[e] = (f16)x;
  }
  f16* dst = (f16*)(ws + WPACK_OFF) + (size_t)layer*WPACK_ELEMS
           + ((size_t)(nt*16+kb)*64 + lane)*8;
  *(f16x8*)dst = v;
}

// 192 WGs = 3 layers x 8 batch-groups x 8 N-groups.
// Weights VGPR-stationary (256 VGPRs/wave of B-fragments; 1 wave/SIMD).
// Cross-WG h: 16B self-validating granules (tag in-band, sc0 sc1); consumers
// poll the DATA (R12's proven full-reload retry). Everything else == R12.
__global__ __launch_bounds__(THREADS, 1) void lstm_ws(
    const float* __restrict__ input,
    const float* __restrict__ bih0, const float* __restrict__ bhh0,
    const float* __restrict__ bih1, const float* __restrict__ bhh1,
    const float* __restrict__ bih2, const float* __restrict__ bhh2,
    const float* __restrict__ wlin, const float* __restrict__ blin,
    unsigned char* __restrict__ ws, float* __restrict__ out)
{
  __shared__ __attribute__((aligned(16))) f16 Hown[ROWS*PITCH];  // 16640 B
  __shared__ __attribute__((aligned(16))) f16 Hin [ROWS*PITCH];  // 16640 B
  __shared__ float wlinLDS[HID];

  const int tid  = threadIdx.x;
  const int w    = tid >> 6;          // 4 waves
  const int wm   = w >> 1, wn = w & 1;
  const int lane = tid & 63;
  const int c16  = lane & 15;
  const int r0   = (lane >> 4) * 4;
  const int bid  = blockIdx.x;
  const int bg   = bid & 7;
  const int nw   = (bid >> 3) & 7;
  const int layer= bid >> 6;
  const int rowsBase = bg * ROWS;
  const int unitBase = nw * 32;
  const int arow = wm*16 + c16;

  int* flags = (int*)ws;
  int* progSelf = flags + (layer*NBG + bg)*8*FLAGSTRIDE;
  int* progUp   = (layer<2)? flags + ((layer+1)*NBG + bg)*8*FLAGSTRIDE : progSelf;

  const f16x8* wpv = (const f16x8*)((const f16*)(ws + WPACK_OFF) + (size_t)layer*WPACK_ELEMS);
  i32x4* ringSelf = (i32x4*)(ws + RING_OFF) + (size_t)((layer*NBG + bg)*DRING)*SLOT_Q;
  i32x4* ringLow  = (layer>0)? (i32x4*)(ws + RING_OFF) + (size_t)(((layer-1)*NBG + bg)*DRING)*SLOT_Q : (i32x4*)0;

  // ---- one-time: this wave's 64 B-fragments -> VGPRs (256 VGPRs) ----
  f16x8 bfr[4][16];
  #pragma unroll
  for (int G=0; G<4; ++G){
    const int nt = G*16 + nw*2 + wn;
    #pragma unroll
    for (int kb=0; kb<16; ++kb)
      bfr[G][kb] = wpv[(size_t)nt*1024 + kb*64 + lane];
  }
  if (tid < HID) wlinLDS[tid] = wlin[tid];

  const float* BIH = (layer==0)?bih0:((layer==1)?bih1:bih2);
  const float* BHH = (layer==0)?bhh0:((layer==1)?bhh1:bhh2);
  float bias[4], cst[4];
  const int unit = unitBase + wn*16 + c16;
  #pragma unroll
  for (int G=0;G<4;++G){
    int n = G*HID + unit;
    bias[G] = BIH[n] + BHH[n];
    cst[G] = 0.f;                                   // reused as [q]
  }
  const float bl = blin[0];
  const int rowblk = wm*4 + (lane>>4);              // this lane's 4-row block
  const int kbv = (layer==0)? 9 : 16;

  for (int i=tid; i<ROWS*PITCH; i+=THREADS){ Hown[i]=(f16)0.f; Hin[i]=(f16)0.f; }
  __syncthreads();

  for (int t=0; t<NSTEPS; ++t){
    // ---- amortized backpressure: every 4th step, upper progress >= t-4 ----
    if (layer<2 && (t&3)==0 && t>4){
      bool act = lane < 8;
      const int* p = progUp + (lane&7)*FLAGSTRIDE;
      int need = act ? t-4 : NEG_INF_I;
      int guard = 0;
      for(;;){
        int v = act ? __hip_atomic_load(p, __ATOMIC_RELAXED, __HIP_MEMORY_SCOPE_AGENT) : 0;
        if (__all(v >= need)) break;
        if (++guard > (1<<18)) break;               // bounded: fail visibly
        __builtin_amdgcn_s_sleep(1);
      }
    }

    // ---- layer-0 input staging (no ring) ----
    if (layer == 0){
      for (int idx=tid; idx<ROWS*12; idx+=THREADS){
        int r = idx/12, i = idx - r*12;
        Hin[r*PITCH + i] = (f16)input[((size_t)t*NBATCH + rowsBase + r)*12 + i];
      }
    }

    // ---- tag-in-band staging: poll data granules until tags current ----
    {
      Gran go[8], gl[8];
      const i32x4* srcO = ringSelf + (size_t)((t-1)&(DRING-1))*SLOT_Q + tid;
      const i32x4* srcL = (layer>0)? ringLow + (size_t)(t&(DRING-1))*SLOT_Q + tid : (i32x4*)0;
      const bool doOwn = (t>0), doLow = (layer>0);
      int guard = 0;
      for(;;){
        if (doOwn){
          #pragma unroll
          for (int it=0; it<8; ++it)
            asm volatile("global_load_dwordx4 %0, %1, off sc0 sc1"
                         : "=v"(go[it].v) : "v"(srcO + it*THREADS) : "memory");
        }
        if (doLow){
          #pragma unroll
          for (int it=0; it<8; ++it)
            asm volatile("global_load_dwordx4 %0, %1, off sc0 sc1"
                         : "=v"(gl[it].v) : "v"(srcL + it*THREADS) : "memory");
        }
        asm volatile("s_waitcnt vmcnt(0)" ::: "memory");
        __builtin_amdgcn_sched_barrier(0);
        bool ok = true;
        if (doOwn){
          #pragma unroll
          for (int it=0; it<8; ++it) ok = ok && (go[it].s.tag >= t-1);
        }
        if (doLow){
          #pragma unroll
          for (int it=0; it<8; ++it) ok = ok && (gl[it].s.tag >= t);
        }
        if (ok || ++guard > (1<<18)) break;          // guard: fail visibly
      }
      if (doOwn){
        #pragma unroll
        for (int it=0; it<8; ++it){
          int i = tid + it*THREADS, rb = i>>8, un = i&255;
          f16* base = &Hown[(rb*4)*PITCH + un];
          base[0]=go[it].s.h[0]; base[PITCH]=go[it].s.h[1];
          base[2*PITCH]=go[it].s.h[2]; base[3*PITCH]=go[it].s.h[3];
        }
      }
      if (doLow){
        #pragma unroll
        for (int it=0; it<8; ++it){
          int i = tid + it*THREADS, rb = i>>8, un = i&255;
          f16* base = &Hin[(rb*4)*PITCH + un];
          base[0]=gl[it].s.h[0]; base[PITCH]=gl[it].s.h[1];
          base[2*PITCH]=gl[it].s.h[2]; base[3*PITCH]=gl[it].s.h[3];
        }
      }
    }
    __syncthreads();                                  // #1: stage -> GEMM

    // ---- progress publish (backpressure producer, off critical path) ----
    if (layer>0 && (t&3)==3 && tid==0)
      __hip_atomic_store(progSelf + nw*FLAGSTRIDE, t+1,
                         __ATOMIC_RELAXED, __HIP_MEMORY_SCOPE_AGENT);

    // ---- gates GEMM (B from VGPRs, A from LDS) + cell ----
    f32x4 acc0={bias[0],bias[0],bias[0],bias[0]};
    f32x4 acc1={bias[1],bias[1],bias[1],bias[1]};
    f32x4 acc2={bias[2],bias[2],bias[2],bias[2]};
    f32x4 acc3={bias[3],bias[3],bias[3],bias[3]};
    #pragma unroll
    for (int kb=0; kb<16; ++kb){
      if (kb < kbv){
        const f16* ap = (kb<8) ? &Hown[arow*PITCH + kb*32 + (lane>>4)*8]
                               : &Hin [arow*PITCH + (kb-8)*32 + (lane>>4)*8];
        f16x8 a = *(const f16x8*)ap;
        acc0 = __builtin_amdgcn_mfma_f32_16x16x32_f16(a, bfr[0][kb], acc0, 0,0,0);
        acc1 = __builtin_amdgcn_mfma_f32_16x16x32_f16(a, bfr[1][kb], acc1, 0,0,0);
        acc2 = __builtin_amdgcn_mfma_f32_16x16x32_f16(a, bfr[2][kb], acc2, 0,0,0);
        acc3 = __builtin_amdgcn_mfma_f32_16x16x32_f16(a, bfr[3][kb], acc3, 0,0,0);
      }
    }

    Gran gg;
    #pragma unroll
    for (int q=0;q<4;++q){
      float gi = sigm  (acc0[q]);
      float gf = sigm  (acc1[q]);
      float gg_ = tanh_f(acc2[q]);
      float go_ = sigm  (acc3[q]);
      float cv = gf*cst[q] + gi*gg_; cst[q]=cv;
      gg.s.h[q] = (f16)(go_*tanh_f(cv));
    }
    gg.s.tag = t; gg.s.pad = 0;
    // ---- publish: ONE self-validating 16B store, fire-and-forget ----
    {
      i32x4* dst = ringSelf + (size_t)(t&(DRING-1))*SLOT_Q + rowblk*256 + unit;
      asm volatile("global_store_dwordx4 %0, %1, off sc0 sc1"
                   :: "v"(dst), "v"(gg.v) : "memory");
    }

    // ---- head (layer 2): out[t-1] from Hown (h_{t-1}) ----
    if (layer==2 && t>0){
      int row = tid>>3, kc = tid&7;
      float s = 0.f;
      #pragma unroll
      for (int cc=0; cc<4; ++cc){
        f16x8 hv = *(const f16x8*)&Hown[row*PITCH + kc*32 + cc*8];
        #pragma unroll
        for (int j=0;j<8;++j) s += (float)hv[j] * wlinLDS[kc*32 + cc*8 + j];
      }
      s += __shfl_xor(s,1); s += __shfl_xor(s,2); s += __shfl_xor(s,4);
      if (kc==0) out[(size_t)(t-1)*NBATCH + rowsBase + row] = s + bl;
    }
    __syncthreads();                                  // #2: reads done -> next stage
  }

  // ---- epilogue: out[511] from h_511 (layer 2) ----
  if (layer==2){
    Gran go[8];
    const i32x4* srcO = ringSelf + (size_t)((NSTEPS-1)&(DRING-1))*SLOT_Q + tid;
    int guard = 0;
    for(;;){
      #pragma unroll
      for (int it=0; it<8; ++it)
        asm volatile("global_load_dwordx4 %0, %1, off sc0 sc1"
                     : "=v"(go[it].v) : "v"(srcO + it*THREADS) : "memory");
      asm volatile("s_waitcnt vmcnt(0)" ::: "memory");
      __builtin_amdgcn_sched_barrier(0);
      bool ok = true;
      #pragma unroll
      for (int it=0; it<8; ++it) ok = ok && (go[it].s.tag >= NSTEPS-1);
      if (ok || ++guard > (1<<18)) break;
    }
    #pragma unroll
    for (int it=0; it<8; ++it){
      int i = tid + it*THREADS, rb = i>>8, un = i&255;
      f16* base = &Hown[(rb*4)*PITCH + un];
      base[0]=go[it].s.h[0]; base[PITCH]=go[it].s.h[1];
      base[2*PITCH]=go[it].s.h[2]; base[3*PITCH]=go[it].s.h[3];
    }
    __syncthreads();
    int row = tid>>3, kc = tid&7;
    float s = 0.f;
    #pragma unroll
    for (int cc=0; cc<4; ++cc){
      f16x8 hv = *(const f16x8*)&Hown[row*PITCH + kc*32 + cc*8];
      #pragma unroll
      for (int j=0;j<8;++j) s += (float)hv[j] * wlinLDS[kc*32 + cc*8 + j];
    }
    s += __shfl_xor(s,1); s += __shfl_xor(s,2); s += __shfl_xor(s,4);
    if (kc==0) out[(size_t)(NSTEPS-1)*NBATCH + rowsBase + row] = s + bl;
  }
}

extern "C" void kernel_launch(void* const* d_in, const int* in_sizes, int n_in,
                              void* d_out, int out_size, void* d_ws, size_t ws_size,
                              hipStream_t stream)
{
  const float* input=(const float*)d_in[0];
  const float* wih0 =(const float*)d_in[1];
  const float* whh0 =(const float*)d_in[2];
  const float* bih0 =(const float*)d_in[3];
  const float* bhh0 =(const float*)d_in[4];
  const float* wih1 =(const float*)d_in[5];
  const float* whh1 =(const float*)d_in[6];
  const float* bih1 =(const float*)d_in[7];
  const float* bhh1 =(const float*)d_in[8];
  const float* wih2 =(const float*)d_in[9];
  const float* whh2 =(const float*)d_in[10];
  const float* bih2 =(const float*)d_in[11];
  const float* bhh2 =(const float*)d_in[12];
  const float* wlin =(const float*)d_in[13];
  const float* blin =(const float*)d_in[14];
  unsigned char* ws = (unsigned char*)d_ws;
  if (ws_size < WS_NEEDED) return;   // ~9.5 MB needed

  (void)hipMemsetAsync(ws, 0, WPACK_OFF, stream);                 // progress flags
  (void)hipMemsetAsync(ws + RING_OFF, 0xFF, RING_SZB, stream);    // ring tags = -1
  hipLaunchKernelGGL(pack_weights, dim3(768), dim3(256), 0, stream,
                     wih0,whh0,wih1,whh1,wih2,whh2, ws);
  hipLaunchKernelGGL(lstm_ws, dim3(NL*NBG*NNW), dim3(THREADS), 0, stream,
                     input, bih0,bhh0,bih1,bhh1,bih2,bhh2, wlin, blin,
                     ws, (float*)d_out);
}